// Round 1
// baseline (323.715 us; speedup 1.0000x reference)
//
#include <hip/hip_runtime.h>
#include <math.h>

// TimeWindowBlock round 6.
// R5 measured 378 us vs ~35 us HBM floor (9% of achievable BW) -> not a
// roofline, a critical-path problem: 53KB LDS hi/lo staging behind a full
// drain barrier at 2 blocks/CU, plus 100 scalar ds_read_u16/thread in
// phase 2. R6 removes the k LDS round-trip entirely:
//  - MFMA A-frags: direct global float4 loads, f32->bf16 hi/lo in regs
//    (fragment pattern = 16 rows x 128B spans per wave-instr, coalesces).
//  - B-frags (c), A, W2: per-lane global loads (L2/L3-hot, zero-padded).
//  - Phase 2: re-read f32 key from global (L2-hot), float4, 16 lanes/row.
// LDS 61KB -> ~6KB, launch_bounds(256,4) -> 4 blocks/CU.

#define BB   512
#define WW   8
#define SS   200
#define HH   64
#define FFN  36

typedef __attribute__((ext_vector_type(8))) short short8;
typedef __attribute__((ext_vector_type(4))) float f32x4;

__device__ __forceinline__ unsigned short f2bf(float x) {
    union { float f; unsigned u; } v; v.f = x;
    unsigned r = v.u + 0x7fffu + ((v.u >> 16) & 1u);   // RNE
    return (unsigned short)(r >> 16);
}
__device__ __forceinline__ float bf2f(unsigned short h) {
    union { unsigned u; float f; } v; v.u = ((unsigned)h) << 16;
    return v.f;
}

// ---------------- kernel A: c_hi[b][48][64] bf16, A[b][48] f32 ----------------
__global__ __launch_bounds__(256)
void precompute_c(const float* __restrict__ query,
                  const float* __restrict__ W1,
                  const float* __restrict__ b1,
                  unsigned short* __restrict__ c_hi_g,
                  float* __restrict__ A_g)
{
    __shared__ float q_s[HH];
    const int b = blockIdx.x, tid = threadIdx.x;
    if (tid < HH) q_s[tid] = query[b * HH + tid];
    __syncthreads();
    for (int idx = tid; idx < 48 * HH; idx += 256) {
        int o = idx >> 6, h = idx & 63;
        float c = 0.0f;
        if (o < FFN) {
            const float* w = W1 + o * 4 * HH;
            c = w[HH + h] - w[2 * HH + h] + w[3 * HH + h] * q_s[h];
        }
        c_hi_g[(size_t)b * 48 * HH + idx] = f2bf(c);
    }
    if (tid < 48) {
        float a = 0.0f;
        if (tid < FFN) {
            const float* w = W1 + tid * 4 * HH;
            a = b1[tid];
            #pragma unroll 8
            for (int h = 0; h < HH; ++h) a += (w[h] + w[2 * HH + h]) * q_s[h];
        }
        A_g[b * 48 + tid] = a;
    }
}

// ---------------- kernel B: main ----------------
__global__ __launch_bounds__(256, 4)
void twb_main(const float* __restrict__ key,
              const unsigned short* __restrict__ c_hi_g,
              const float* __restrict__ A_g,
              const float* __restrict__ prelu_a,
              const float* __restrict__ W2,
              const int*   __restrict__ mask,
              float*       __restrict__ out)
{
    __shared__ float scores[208];
    __shared__ float wl[208];
    __shared__ float red[8];
    __shared__ float4 part4[256];

    const int tid  = threadIdx.x;
    const int bw   = blockIdx.x;
    const int b    = bw >> 3;
    const int lane = tid & 63, q = lane >> 4, n = lane & 15, wid = tid >> 6;

    const float* kg = key + (size_t)bw * (SS * HH);
    const unsigned short* cb = c_hi_g + (size_t)b * 48 * HH;

    // ---- per-lane parameter prefetch (L2/L3-hot, zero-padded to 48) ----
    short8 Bf[3][2];
    float  Ao[3], w2o[3];
    #pragma unroll
    for (int ot = 0; ot < 3; ++ot) {
        const int o = ot * 16 + n;
        #pragma unroll
        for (int ks = 0; ks < 2; ++ks)
            Bf[ot][ks] = *(const short8*)(cb + (size_t)o * HH + ks * 32 + q * 8);
        Ao[ot]  = A_g[b * 48 + o];
        w2o[ot] = (o < FFN) ? W2[o] : 0.0f;
    }
    int mv = 1;
    if (tid < SS) mv = mask[bw * SS + tid];
    const float pa = prelu_a[0];

    // ---- phase 1: MFMA score GEMM, A-frags direct from global ----
    for (int st = wid; st < 13; st += 4) {
        const int s = st * 16 + n;
        short8 Ah[2], Al[2];
        if (s < SS) {
            #pragma unroll
            for (int ks = 0; ks < 2; ++ks) {
                const float* p = kg + s * HH + ks * 32 + q * 8;
                const float4 v0 = *(const float4*)p;
                const float4 v1 = *(const float4*)(p + 4);
                const float vv[8] = {v0.x, v0.y, v0.z, v0.w,
                                     v1.x, v1.y, v1.z, v1.w};
                #pragma unroll
                for (int j = 0; j < 8; ++j) {
                    const unsigned short hi = f2bf(vv[j]);
                    Ah[ks][j] = (short)hi;
                    Al[ks][j] = (short)f2bf(vv[j] - bf2f(hi));
                }
            }
        } else {
            #pragma unroll
            for (int ks = 0; ks < 2; ++ks)
                #pragma unroll
                for (int j = 0; j < 8; ++j) { Ah[ks][j] = 0; Al[ks][j] = 0; }
        }
        float contrib[4] = {0.f, 0.f, 0.f, 0.f};
        #pragma unroll
        for (int ot = 0; ot < 3; ++ot) {
            f32x4 acc = {0.f, 0.f, 0.f, 0.f};
            acc = __builtin_amdgcn_mfma_f32_16x16x32_bf16(Ah[0], Bf[ot][0], acc, 0, 0, 0);
            acc = __builtin_amdgcn_mfma_f32_16x16x32_bf16(Al[0], Bf[ot][0], acc, 0, 0, 0);
            acc = __builtin_amdgcn_mfma_f32_16x16x32_bf16(Ah[1], Bf[ot][1], acc, 0, 0, 0);
            acc = __builtin_amdgcn_mfma_f32_16x16x32_bf16(Al[1], Bf[ot][1], acc, 0, 0, 0);
            #pragma unroll
            for (int r = 0; r < 4; ++r) {
                float hv = acc[r] + Ao[ot];
                hv = (hv >= 0.0f) ? hv : pa * hv;
                contrib[r] += w2o[ot] * hv;
            }
        }
        #pragma unroll
        for (int m = 1; m <= 8; m <<= 1)
            #pragma unroll
            for (int r = 0; r < 4; ++r)
                contrib[r] += __shfl_xor(contrib[r], m, 64);
        if (n == 0) {
            #pragma unroll
            for (int r = 0; r < 4; ++r) {
                const int s2 = st * 16 + q * 4 + r;
                if (s2 < SS) scores[s2] = contrib[r];
            }
        }
    }
    __syncthreads();

    // ---- mask + softmax over S ----
    float msc = -3.0e38f;
    if (tid < SS)
        msc = mv ? -10000.0f : scores[tid];
    float mx = msc;
    #pragma unroll
    for (int off = 32; off > 0; off >>= 1)
        mx = fmaxf(mx, __shfl_xor(mx, off, 64));
    if (lane == 0) red[wid] = mx;
    __syncthreads();
    const float M = fmaxf(fmaxf(red[0], red[1]), fmaxf(red[2], red[3]));
    float e = (tid < SS) ? __expf(msc - M) : 0.0f;
    float ssum = e;
    #pragma unroll
    for (int off = 32; off > 0; off >>= 1)
        ssum += __shfl_xor(ssum, off, 64);
    if (lane == 0) red[4 + wid] = ssum;
    __syncthreads();
    const float total = red[4] + red[5] + red[6] + red[7];
    if (tid < SS) wl[tid] = e / total;
    __syncthreads();

    // ---- phase 2: out[h] = sum_s k[s][h] * wl[s], f32 from global (L2-hot) ----
    {
        const int r0 = tid >> 4;            // 0..15: starting row
        const int h4 = (tid & 15) * 4;      // float4 column
        float4 acc2 = {0.f, 0.f, 0.f, 0.f};
        for (int s = r0; s < SS; s += 16) {
            const float4 kv = *(const float4*)(kg + s * HH + h4);
            const float w = wl[s];
            acc2.x += kv.x * w; acc2.y += kv.y * w;
            acc2.z += kv.z * w; acc2.w += kv.w * w;
        }
        part4[tid] = acc2;
    }
    __syncthreads();
    if (tid < HH) {
        const int hg = tid >> 2, c = tid & 3;
        float r = 0.0f;
        #pragma unroll
        for (int row = 0; row < 16; ++row)
            r += ((const float*)&part4[row * 16 + hg])[c];
        out[(size_t)bw * HH + tid] = r;
    }
}

// ---------------- fallback (round-1 kernel, used if ws too small) ----------------
#define PADQ 17
__global__ __launch_bounds__(256, 2)
void twb_fallback(const float* __restrict__ query,
                  const float* __restrict__ key,
                  const float* __restrict__ W1,
                  const float* __restrict__ b1,
                  const float* __restrict__ prelu_a,
                  const float* __restrict__ W2,
                  const float* __restrict__ b2,
                  const int*   __restrict__ mask,
                  float*       __restrict__ out)
{
    __shared__ float q_s[HH];
    __shared__ float c_s[FFN * HH];
    __shared__ float A_s[FFN];
    __shared__ float W2_s[FFN];
    __shared__ float k_s[SS * PADQ * 4];
    __shared__ float wl[256];
    __shared__ float red[8];
    __shared__ float part[4 * 64];

    const int tid = threadIdx.x;
    const int bw  = blockIdx.x;
    const int b   = bw >> 3;

    if (tid < HH)  q_s[tid]  = query[b * HH + tid];
    if (tid < FFN) W2_s[tid] = W2[tid];
    __syncthreads();

    const float4* gk4 = (const float4*)(key + (size_t)bw * (SS * HH));
    float4* kl4 = (float4*)k_s;
    for (int i = tid; i < (SS * HH) / 4; i += 256) {
        float4 v = gk4[i];
        kl4[(i >> 4) * PADQ + (i & 15)] = v;
    }
    for (int idx = tid; idx < FFN * HH; idx += 256) {
        int o = idx >> 6, h = idx & 63;
        const float* w = W1 + o * (4 * HH);
        c_s[idx] = w[HH + h] - w[2 * HH + h] + w[3 * HH + h] * q_s[h];
    }
    if (tid < FFN) {
        const float* w = W1 + tid * (4 * HH);
        float a = b1[tid];
        for (int h = 0; h < HH; ++h) a += (w[h] + w[2 * HH + h]) * q_s[h];
        A_s[tid] = a;
    }
    __syncthreads();

    const float pa  = prelu_a[0];
    const float bb2 = b2[0];
    float msc = -3.0e38f;
    if (tid < SS) {
        float acc[FFN];
        #pragma unroll
        for (int o = 0; o < FFN; ++o) acc[o] = A_s[o];
        const float4* c4 = (const float4*)c_s;
        const float4* k4 = (const float4*)k_s;
        const int rowbase = tid * PADQ;
        for (int ch = 0; ch < 4; ++ch) {
            float4 kv0 = k4[rowbase + ch * 4 + 0];
            float4 kv1 = k4[rowbase + ch * 4 + 1];
            float4 kv2 = k4[rowbase + ch * 4 + 2];
            float4 kv3 = k4[rowbase + ch * 4 + 3];
            #pragma unroll
            for (int o = 0; o < FFN; ++o) {
                float4 c0 = c4[o * 16 + ch * 4 + 0];
                float4 c1 = c4[o * 16 + ch * 4 + 1];
                float4 c2 = c4[o * 16 + ch * 4 + 2];
                float4 c3 = c4[o * 16 + ch * 4 + 3];
                float a = acc[o];
                a += c0.x * kv0.x + c0.y * kv0.y + c0.z * kv0.z + c0.w * kv0.w;
                a += c1.x * kv1.x + c1.y * kv1.y + c1.z * kv1.z + c1.w * kv1.w;
                a += c2.x * kv2.x + c2.y * kv2.y + c2.z * kv2.z + c2.w * kv2.w;
                a += c3.x * kv3.x + c3.y * kv3.y + c3.z * kv3.z + c3.w * kv3.w;
                acc[o] = a;
            }
        }
        float sc = bb2;
        #pragma unroll
        for (int o = 0; o < FFN; ++o) {
            float a = acc[o];
            a = (a >= 0.0f) ? a : pa * a;
            sc += W2_s[o] * a;
        }
        msc = mask[bw * SS + tid] ? -10000.0f : sc;
    }

    float mx = msc;
    #pragma unroll
    for (int off = 32; off > 0; off >>= 1)
        mx = fmaxf(mx, __shfl_xor(mx, off, 64));
    const int wid = tid >> 6;
    if ((tid & 63) == 0) red[wid] = mx;
    __syncthreads();
    const float M = fmaxf(fmaxf(red[0], red[1]), fmaxf(red[2], red[3]));
    float e = (tid < SS) ? __expf(msc - M) : 0.0f;
    float ssum = e;
    #pragma unroll
    for (int off = 32; off > 0; off >>= 1)
        ssum += __shfl_xor(ssum, off, 64);
    if ((tid & 63) == 0) red[4 + wid] = ssum;
    __syncthreads();
    const float total = red[4] + red[5] + red[6] + red[7];
    if (tid < SS) wl[tid] = e / total;
    __syncthreads();

    const int wv = tid >> 6, h = tid & 63;
    float p = 0.0f;
    for (int s = wv * 50; s < wv * 50 + 50; ++s)
        p += k_s[s * (PADQ * 4) + h] * wl[s];
    part[wv * 64 + h] = p;
    __syncthreads();
    if (tid < 64) {
        float r = part[tid] + part[64 + tid] + part[128 + tid] + part[192 + tid];
        out[(size_t)bw * HH + tid] = r;
    }
}

extern "C" void kernel_launch(void* const* d_in, const int* in_sizes, int n_in,
                              void* d_out, int out_size, void* d_ws, size_t ws_size,
                              hipStream_t stream) {
    const float* query   = (const float*)d_in[0];
    const float* key     = (const float*)d_in[1];
    const float* W1      = (const float*)d_in[2];
    const float* b1      = (const float*)d_in[3];
    const float* prelu_a = (const float*)d_in[4];
    const float* W2      = (const float*)d_in[5];
    const float* b2      = (const float*)d_in[6];
    const int*   mask    = (const int*)d_in[7];
    float* out = (float*)d_out;

    const size_t c_bytes = (size_t)BB * 48 * HH * sizeof(unsigned short); // 3.15 MB
    const size_t a_bytes = (size_t)BB * 48 * sizeof(float);               // 98 KB
    if (ws_size >= c_bytes + a_bytes) {
        unsigned short* c_hi_g = (unsigned short*)d_ws;
        float* A_g = (float*)((char*)d_ws + c_bytes);
        precompute_c<<<BB, 256, 0, stream>>>(query, W1, b1, c_hi_g, A_g);
        twb_main<<<BB * WW, 256, 0, stream>>>(key, c_hi_g, A_g, prelu_a,
                                              W2, mask, out);
    } else {
        twb_fallback<<<BB * WW, 256, 0, stream>>>(query, key, W1, b1, prelu_a,
                                                  W2, b2, mask, out);
    }
}